// Round 7
// baseline (41157.196 us; speedup 1.0000x reference)
//
#include <hip/hip_runtime.h>
#include <cstdint>
#include <cstddef>

// B=256 batch, n=512 classes/steps, H=512 hidden, 3H=1536.
#define BB 256
#define NN 512
#define HH 512
#define G3 1536

typedef short bf16x8 __attribute__((ext_vector_type(8)));
typedef float f32x4 __attribute__((ext_vector_type(4)));

// ---------------- static device state ----------------
// Weight planes (hi then lo), MFMA fragment order. 1536-row weights use
// GATE-INTERLEAVED tiles: tile(c) = ((c&511)>>4)*3 + (c>>9); W_out: tile=c>>4.
// Fragment offset: (tile*16 + S)*512 + qu*128 + ci*8 + j.
__device__ __align__(16) short g_Whh0[2 * 786432];
__device__ __align__(16) short g_Whh1[2 * 786432];
__device__ __align__(16) short g_Wih1[2 * 786432];
__device__ __align__(16) short g_Wout[2 * 262144];
// h-state bf16 hi/lo planes, double buffered by parity; A-fragment order:
// off(b,h) = (b>>4)*8192 + (h>>5)*512 + ((h>>3)&3)*128 + (b&15)*8 + (h&7)
__device__ __align__(16) short g_h0p[2][2 * 131072];
__device__ __align__(16) short g_h1p[2][2 * 131072];
__device__ __align__(16) float g_gh1[BB * G3];       // [b][g*512+h] incl b_hh1
__device__ __align__(16) float g_logits[BB * NN];    // step-local, incl b_out
__device__ __align__(16) float g_WihT[NN * G3];      // W_ih0^T (constant)
__device__ __align__(16) float g_ones[G3];           // gi0 at t=0 (incl b_ih0)
__device__ __align__(16) float g_gum[NN][BB][NN];    // 256 MB precomputed
__device__ int g_idx[BB];
__device__ unsigned g_bar[16 * 32];  // per-mt monotonic barrier counter

// ---------------- sc1 (agent-scope relaxed) access ----------------
__device__ __forceinline__ unsigned long long cload_u64(const void* p) {
  return __hip_atomic_load((const unsigned long long*)p, __ATOMIC_RELAXED,
                           __HIP_MEMORY_SCOPE_AGENT);
}
__device__ __forceinline__ bf16x8 cload_frag(const short* p) {
  union { unsigned long long q[2]; bf16x8 v; } u;
  u.q[0] = cload_u64(p);
  u.q[1] = cload_u64(p + 4);
  return u.v;
}
__device__ __forceinline__ float cloadf(const float* p) {
  return __hip_atomic_load(p, __ATOMIC_RELAXED, __HIP_MEMORY_SCOPE_AGENT);
}
__device__ __forceinline__ void cstoref(float* p, float v) {
  __hip_atomic_store(p, v, __ATOMIC_RELAXED, __HIP_MEMORY_SCOPE_AGENT);
}
__device__ __forceinline__ void cstores(short* p, short v) {
  __hip_atomic_store((unsigned short*)p, (unsigned short)v, __ATOMIC_RELAXED,
                     __HIP_MEMORY_SCOPE_AGENT);
}

// ---------------- bf16 hi/lo helpers ----------------
__device__ __forceinline__ unsigned short bf16_rne(float f) {
  uint32_t u = __float_as_uint(f);
  uint32_t r = u + 0x7FFFu + ((u >> 16) & 1u);
  return (unsigned short)(r >> 16);
}
__device__ __forceinline__ float bf16_to_f(unsigned short h) {
  return __uint_as_float(((uint32_t)h) << 16);
}
__device__ __forceinline__ float sigf(float x) {
  return 1.0f / (1.0f + expf(-x));
}
__device__ __forceinline__ f32x4 mfma16(bf16x8 a, bf16x8 b, f32x4 c) {
  return __builtin_amdgcn_mfma_f32_16x16x32_bf16(a, b, c, 0, 0, 0);
}
__device__ __forceinline__ void store_h_plane(short* plane, int b, int h,
                                              float v) {
  int off = (b >> 4) * 8192 + (h >> 5) * 512 + ((h >> 3) & 3) * 128 +
            (b & 15) * 8 + (h & 7);
  unsigned short hi = bf16_rne(v);
  cstores(plane + off, (short)hi);
  cstores(plane + 131072 + off, (short)bf16_rne(v - bf16_to_f(hi)));
}

// ---------------- threefry2x32 (JAX-exact, 20 rounds) ----------------
__device__ __forceinline__ uint32_t rotl32(uint32_t v, int r) {
  return (v << r) | (v >> (32 - r));
}
__device__ __forceinline__ void threefry2x32(uint32_t k0, uint32_t k1,
                                             uint32_t x0, uint32_t x1,
                                             uint32_t& o0, uint32_t& o1) {
  uint32_t k2 = k0 ^ k1 ^ 0x1BD11BDAu;
  x0 += k0; x1 += k1;
  x0 += x1; x1 = rotl32(x1, 13); x1 ^= x0;
  x0 += x1; x1 = rotl32(x1, 15); x1 ^= x0;
  x0 += x1; x1 = rotl32(x1, 26); x1 ^= x0;
  x0 += x1; x1 = rotl32(x1, 6);  x1 ^= x0;
  x0 += k1; x1 += k2 + 1u;
  x0 += x1; x1 = rotl32(x1, 17); x1 ^= x0;
  x0 += x1; x1 = rotl32(x1, 29); x1 ^= x0;
  x0 += x1; x1 = rotl32(x1, 16); x1 ^= x0;
  x0 += x1; x1 = rotl32(x1, 24); x1 ^= x0;
  x0 += k2; x1 += k0 + 2u;
  x0 += x1; x1 = rotl32(x1, 13); x1 ^= x0;
  x0 += x1; x1 = rotl32(x1, 15); x1 ^= x0;
  x0 += x1; x1 = rotl32(x1, 26); x1 ^= x0;
  x0 += x1; x1 = rotl32(x1, 6);  x1 ^= x0;
  x0 += k0; x1 += k1 + 3u;
  x0 += x1; x1 = rotl32(x1, 17); x1 ^= x0;
  x0 += x1; x1 = rotl32(x1, 29); x1 ^= x0;
  x0 += x1; x1 = rotl32(x1, 16); x1 ^= x0;
  x0 += x1; x1 = rotl32(x1, 24); x1 ^= x0;
  x0 += k1; x1 += k2 + 4u;
  x0 += x1; x1 = rotl32(x1, 13); x1 ^= x0;
  x0 += x1; x1 = rotl32(x1, 15); x1 ^= x0;
  x0 += x1; x1 = rotl32(x1, 26); x1 ^= x0;
  x0 += x1; x1 = rotl32(x1, 6);  x1 ^= x0;
  x0 += k2; x1 += k0 + 5u;
  o0 = x0; o1 = x1;
}
__device__ __forceinline__ float gumbel_from_bits(uint32_t bits) {
  float u = __uint_as_float((bits >> 9) | 0x3f800000u) - 1.0f;
  if (u == 0.0f) u = 1.17549435e-38f;
  return -logf(-logf(u));
}

// ---------------- prelude kernels ----------------
__global__ __launch_bounds__(256) void init_state_kernel() {
  int i = blockIdx.x * 256 + threadIdx.x;  // 1024 blocks
  if (i < 262144) {  // zero all parities+planes (524288 shorts each array)
    ((uint32_t*)g_h0p)[i] = 0u;
    ((uint32_t*)g_h1p)[i] = 0u;
  }
  if (i < 16 * 32) g_bar[i] = 0u;
  if (i < BB) g_idx[i] = 0;
}

__global__ __launch_bounds__(256) void ones_row_kernel(
    const float* __restrict__ W_ih0, const float* __restrict__ b_ih0) {
  int j = blockIdx.x * 256 + threadIdx.x;
  if (j < G3) {
    const float* row = W_ih0 + (size_t)j * NN;
    float s = 0.0f;
    for (int k = 0; k < NN; ++k) s += row[k];
    g_ones[j] = s + b_ih0[j];
  }
}

__global__ __launch_bounds__(256) void transpose_kernel(
    const float* __restrict__ in) {
  __shared__ float tile[32][33];
  int bx = blockIdx.x, by = blockIdx.y;
  int tx = threadIdx.x & 31, ty = threadIdx.x >> 5;
  for (int i = 0; i < 32; i += 8)
    tile[ty + i][tx] = in[(size_t)(by * 32 + ty + i) * NN + bx * 32 + tx];
  __syncthreads();
  for (int i = 0; i < 32; i += 8)
    g_WihT[(size_t)(bx * 32 + ty + i) * G3 + by * 32 + tx] = tile[tx][ty + i];
}

__global__ __launch_bounds__(256) void split_kernel(
    const float* __restrict__ W, short* __restrict__ dst, int rows,
    int plane) {
  int i = blockIdx.x * 256 + threadIdx.x;
  if (i >= rows * 64) return;
  int c = i >> 6, jb = i & 63, ci = c & 15;
  int tile = (rows == G3) ? (((c & 511) >> 4) * 3 + (c >> 9)) : (c >> 4);
  int S = jb >> 2, qu = jb & 3;
  int off = (tile * 16 + S) * 512 + qu * 128 + ci * 8;
  const float* src = W + (size_t)c * 512 + jb * 8;
  float v[8];
  *(float4*)v = *(const float4*)src;
  *(float4*)(v + 4) = *(const float4*)(src + 4);
  short hb[8], lb[8];
#pragma unroll
  for (int e = 0; e < 8; ++e) {
    unsigned short h = bf16_rne(v[e]);
    hb[e] = (short)h;
    lb[e] = (short)bf16_rne(v[e] - bf16_to_f(h));
  }
  *(bf16x8*)(dst + off) = *(const bf16x8*)hb;
  *(bf16x8*)(dst + plane + off) = *(const bf16x8*)lb;
}

// Precompute all gumbels: grid 512 (one block per step t), 256 threads.
__global__ __launch_bounds__(256) void gumbel_kernel() {
  const int t = blockIdx.x;
  uint32_t tp = (uint32_t)(t & 255);
  uint32_t a0, a1, c0, c1;
  threefry2x32(0u, 42u, 2u * tp, 2u * tp + 512u, a0, a1);
  threefry2x32(0u, 42u, 2u * tp + 1u, 2u * tp + 1u + 512u, c0, c1);
  uint32_t sk0 = (t < 256) ? a0 : a1;
  uint32_t sk1 = (t < 256) ? c0 : c1;
  for (int i = threadIdx.x; i < 65536; i += 256) {
    int b = i >> 9, c = i & 511;
    uint32_t cnt = (uint32_t)b * 512u + (uint32_t)c;
    uint32_t r0, r1;
    threefry2x32(sk0, sk1, cnt, cnt + 65536u, r0, r1);
    g_gum[t][b][c] = gumbel_from_bits(r0);
    g_gum[t][b + 128][c] = gumbel_from_bits(r1);
  }
}

// ---------------- mt-local 16-block barrier (monotonic, no invalidate) -----
__device__ __forceinline__ void gbar(int mt, unsigned target) {
  __syncthreads();
  if (threadIdx.x == 0) {
    __hip_atomic_fetch_add(&g_bar[mt * 32], 1u, __ATOMIC_RELEASE,
                           __HIP_MEMORY_SCOPE_AGENT);
    while (__hip_atomic_load(&g_bar[mt * 32], __ATOMIC_RELAXED,
                             __HIP_MEMORY_SCOPE_AGENT) < target)
      __builtin_amdgcn_s_sleep(2);
  }
  asm volatile("" ::: "memory");  // block compiler motion across the barrier
  __syncthreads();
}

// ---------------- persistent kernel ----------------
// bid: mt = bid>>4 (16 batch rows), nb = bid&15 (XCD = bid%8 -> nb%8: each
// XCD hosts 2 nb weight slices, ~1.25 MB, L2-resident). 256 thr = 4 waves.
// Per step: ph1 gh0+cell0 (nb<8) || gh1 (nb>=8); ph2 gi1+cell1 (nb<8);
// ph3 logits (nb<8); ph4 sample (nb==0). 4 mt-local barriers.
__global__ __launch_bounds__(256) void persist_kernel(
    const float* __restrict__ b_ih0, const float* __restrict__ b_hh0,
    const float* __restrict__ b_ih1, const float* __restrict__ b_hh1,
    const float* __restrict__ b_out, float* __restrict__ out_perm,
    float* __restrict__ out_lp) {
  const int bid = blockIdx.x;
  const int mt = bid >> 4, nb = bid & 15;
  const int tid = threadIdx.x;
  const int w = tid >> 6, ln = tid & 63;
  const int ci = ln & 15, qu = ln >> 4;
  const int lnoff = ln * 8;

  __shared__ unsigned savail[16][16];
  __shared__ float slp[16];
  __shared__ float sred[512];  // argmax/sum scratch (v,i interleaved use)
  __shared__ int sidx[256];

  if (nb == 0) {
    if (tid < 16) slp[tid] = 0.0f;
    for (int i = tid; i < 256; i += 256) savail[i >> 4][i & 15] = 0xFFFFFFFFu;
  }
  __syncthreads();

  float h0prev[4] = {0.f, 0.f, 0.f, 0.f};
  float h1prev[4] = {0.f, 0.f, 0.f, 0.f};
  unsigned ep = 0;

  for (int t = 0; t < NN; ++t) {
    const int p = t & 1, pw = p ^ 1;

    // ---------------- phase 1 ----------------
    {
      const int u = (nb & 7) * 4 + w;
      const short* Ap = (nb < 8) ? g_h0p[p] : g_h1p[p];
      const short* Wp = (nb < 8) ? g_Whh0 : g_Whh1;
      f32x4 z = (f32x4){0.f, 0.f, 0.f, 0.f};
      f32x4 acc[3] = {z, z, z};
#pragma unroll
      for (int S = 0; S < 16; ++S) {
        const int aoff = mt * 8192 + S * 512 + lnoff;
        bf16x8 ah = cload_frag(Ap + aoff);
        bf16x8 al = cload_frag(Ap + 131072 + aoff);
#pragma unroll
        for (int g = 0; g < 3; ++g) {
          const short* wp = Wp + ((u * 3 + g) * 16 + S) * 512 + lnoff;
          bf16x8 bh = *(const bf16x8*)wp;
          bf16x8 bl = *(const bf16x8*)(wp + 786432);
          acc[g] = mfma16(ah, bh, acc[g]);
          acc[g] = mfma16(ah, bl, acc[g]);
          acc[g] = mfma16(al, bh, acc[g]);
        }
      }
      const int h = u * 16 + ci;
      if (nb < 8) {
        const float br = b_hh0[h], bz = b_hh0[HH + h], bn = b_hh0[2 * HH + h];
        const float bi0 = b_ih0[h], bi1 = b_ih0[HH + h],
                    bi2 = b_ih0[2 * HH + h];
#pragma unroll
        for (int r = 0; r < 4; ++r) {
          const int b = mt * 16 + qu * 4 + r;
          float ir, iz, in_;
          if (t == 0) {
            ir = g_ones[h]; iz = g_ones[HH + h]; in_ = g_ones[2 * HH + h];
          } else {
            int iv = __hip_atomic_load(&g_idx[b], __ATOMIC_RELAXED,
                                       __HIP_MEMORY_SCOPE_AGENT);
            const float* wr_ = g_WihT + (size_t)iv * G3;
            ir = wr_[h] + bi0;
            iz = wr_[HH + h] + bi1;
            in_ = wr_[2 * HH + h] + bi2;
          }
          float rr_ = sigf(ir + acc[0][r] + br);
          float zz = sigf(iz + acc[1][r] + bz);
          float ng = tanhf(in_ + rr_ * (acc[2][r] + bn));
          float hn = (1.f - zz) * ng + zz * h0prev[r];
          h0prev[r] = hn;
          store_h_plane(g_h0p[pw], b, h, hn);
        }
      } else {
        const float c0 = b_hh1[h], c1 = b_hh1[HH + h], c2 = b_hh1[2 * HH + h];
#pragma unroll
        for (int r = 0; r < 4; ++r) {
          const int b = mt * 16 + qu * 4 + r;
          float* base = g_gh1 + (size_t)b * G3;
          cstoref(base + h, acc[0][r] + c0);
          cstoref(base + 512 + h, acc[1][r] + c1);
          cstoref(base + 1024 + h, acc[2][r] + c2);
        }
      }
    }
    gbar(mt, 16u * (++ep));

    // ---------------- phase 2: gi1 + cell1 (nb<8) ----------------
    if (nb < 8) {
      const int u = nb * 4 + w;
      f32x4 z = (f32x4){0.f, 0.f, 0.f, 0.f};
      f32x4 acc[3] = {z, z, z};
#pragma unroll
      for (int S = 0; S < 16; ++S) {
        const int aoff = mt * 8192 + S * 512 + lnoff;
        bf16x8 ah = cload_frag(g_h0p[pw] + aoff);
        bf16x8 al = cload_frag(g_h0p[pw] + 131072 + aoff);
#pragma unroll
        for (int g = 0; g < 3; ++g) {
          const short* wp = g_Wih1 + ((u * 3 + g) * 16 + S) * 512 + lnoff;
          bf16x8 bh = *(const bf16x8*)wp;
          bf16x8 bl = *(const bf16x8*)(wp + 786432);
          acc[g] = mfma16(ah, bh, acc[g]);
          acc[g] = mfma16(ah, bl, acc[g]);
          acc[g] = mfma16(al, bh, acc[g]);
        }
      }
      const int h = u * 16 + ci;
      const float bi0 = b_ih1[h], bi1 = b_ih1[HH + h], bi2 = b_ih1[2 * HH + h];
#pragma unroll
      for (int r = 0; r < 4; ++r) {
        const int b = mt * 16 + qu * 4 + r;
        const float* base = g_gh1 + (size_t)b * G3;
        float rr_ = sigf(acc[0][r] + bi0 + cloadf(base + h));
        float zz = sigf(acc[1][r] + bi1 + cloadf(base + 512 + h));
        float ng = tanhf(acc[2][r] + bi2 + rr_ * cloadf(base + 1024 + h));
        float hn = (1.f - zz) * ng + zz * h1prev[r];
        h1prev[r] = hn;
        store_h_plane(g_h1p[pw], b, h, hn);
      }
    }
    gbar(mt, 16u * (++ep));

    // ---------------- phase 3: logits (nb<8) ----------------
    if (nb < 8) {
      const int u = nb * 4 + w;  // n-tile 0..31
      f32x4 a1 = (f32x4){0.f, 0.f, 0.f, 0.f};
#pragma unroll
      for (int S = 0; S < 16; ++S) {
        const int aoff = mt * 8192 + S * 512 + lnoff;
        bf16x8 ah = cload_frag(g_h1p[pw] + aoff);
        bf16x8 al = cload_frag(g_h1p[pw] + 131072 + aoff);
        const short* wp = g_Wout + (u * 16 + S) * 512 + lnoff;
        bf16x8 bh = *(const bf16x8*)wp;
        bf16x8 bl = *(const bf16x8*)(wp + 262144);
        a1 = mfma16(ah, bh, a1);
        a1 = mfma16(ah, bl, a1);
        a1 = mfma16(al, bh, a1);
      }
      const int n = u * 16 + ci;
      const float bo = b_out[n];
#pragma unroll
      for (int r = 0; r < 4; ++r) {
        const int b = mt * 16 + qu * 4 + r;
        cstoref(&g_logits[b * NN + n], a1[r] + bo);
      }
    }
    gbar(mt, 16u * (++ep));

    // ---------------- phase 4: sample (nb==0) ----------------
    if (nb == 0) {
      const int r = tid >> 4, l16 = tid & 15;  // row, sub-lane
      const int b = mt * 16 + r;
      const float* grow = &g_gum[t][b][0];
      float best = -1.0f / 0.0f;
      int bi = 0;
      float sum = 0.0f;
#pragma unroll 4
      for (int k = 0; k < 32; ++k) {
        int c = l16 + k * 16;
        float l = cloadf(&g_logits[b * NN + c]);
        float g = grow[c];
        bool av = (savail[r][c >> 5] >> (c & 31)) & 1u;
        float ml = av ? l : -1.0e9f;
        float v = g + ml;
        if (v > best || (v == best && c < bi)) { best = v; bi = c; }
        sum += av ? expf(l) : 0.0f;
      }
      sred[tid] = best; sidx[tid] = bi; sred[256 + tid] = sum;
      __syncthreads();
      for (int s = 8; s > 0; s >>= 1) {
        if (l16 < s) {
          float v2 = sred[tid + s]; int i2 = sidx[tid + s];
          if (v2 > sred[tid] || (v2 == sred[tid] && i2 < sidx[tid])) {
            sred[tid] = v2; sidx[tid] = i2;
          }
          sred[256 + tid] += sred[256 + tid + s];
        }
        __syncthreads();
      }
      const int sel = sidx[r * 16];
      if (l16 == 0) {
        float ssum = sred[256 + r * 16];
        float lsel = cloadf(&g_logits[b * NN + sel]);
        float pz = expf(lsel) / ssum;
        slp[r] += logf(pz + 1e-9f);
        savail[r][sel >> 5] &= ~(1u << (sel & 31));
        __hip_atomic_store(&g_idx[b], sel, __ATOMIC_RELAXED,
                           __HIP_MEMORY_SCOPE_AGENT);
        out_perm[(size_t)b * NN * NN + (size_t)t * NN + sel] = 1.0f;
        if (t == NN - 1) out_lp[b] = slp[r];
      }
      __syncthreads();
    }
    gbar(mt, 16u * (++ep));
  }
}

// ---------------- host ----------------
extern "C" void kernel_launch(void* const* d_in, const int* in_sizes, int n_in,
                              void* d_out, int out_size, void* d_ws,
                              size_t ws_size, hipStream_t stream) {
  (void)in_sizes; (void)n_in; (void)d_ws; (void)ws_size;
  const float* W_ih0 = (const float*)d_in[1];
  const float* W_hh0 = (const float*)d_in[2];
  const float* b_ih0 = (const float*)d_in[3];
  const float* b_hh0 = (const float*)d_in[4];
  const float* W_ih1 = (const float*)d_in[5];
  const float* W_hh1 = (const float*)d_in[6];
  const float* b_ih1 = (const float*)d_in[7];
  const float* b_hh1 = (const float*)d_in[8];
  const float* W_out = (const float*)d_in[9];
  const float* b_out = (const float*)d_in[10];

  float* out = (float*)d_out;
  float* out_lp = out + (size_t)BB * NN * NN;

  hipMemsetAsync(d_out, 0, (size_t)out_size * sizeof(float), stream);
  init_state_kernel<<<1024, 256, 0, stream>>>();
  ones_row_kernel<<<6, 256, 0, stream>>>(W_ih0, b_ih0);
  transpose_kernel<<<dim3(16, 48), 256, 0, stream>>>(W_ih0);
  gumbel_kernel<<<512, 256, 0, stream>>>();

  short* whh0; hipGetSymbolAddress((void**)&whh0, HIP_SYMBOL(g_Whh0));
  short* whh1; hipGetSymbolAddress((void**)&whh1, HIP_SYMBOL(g_Whh1));
  short* wih1; hipGetSymbolAddress((void**)&wih1, HIP_SYMBOL(g_Wih1));
  short* wout; hipGetSymbolAddress((void**)&wout, HIP_SYMBOL(g_Wout));
  split_kernel<<<384, 256, 0, stream>>>(W_hh0, whh0, G3, 786432);
  split_kernel<<<384, 256, 0, stream>>>(W_hh1, whh1, G3, 786432);
  split_kernel<<<384, 256, 0, stream>>>(W_ih1, wih1, G3, 786432);
  split_kernel<<<128, 256, 0, stream>>>(W_out, wout, NN, 262144);

  persist_kernel<<<256, 256, 0, stream>>>(b_ih0, b_hh0, b_ih1, b_hh1, b_out,
                                          out, out_lp);
}